// Round 6
// baseline (591.999 us; speedup 1.0000x reference)
//
#include <hip/hip_runtime.h>
#include <hip/hip_bf16.h>
#include <stdint.h>

typedef __hip_bfloat16 bf16;
typedef short short4v __attribute__((ext_vector_type(4)));
typedef short short8 __attribute__((ext_vector_type(8)));
typedef float f32x4 __attribute__((ext_vector_type(4)));

#define NB 128
#define NPIX 196      // 14*14
#define NPAD 208      // 13*16
#define VP 224        // v4 row pitch (7*32 for PV k-steps), cols [208,224) zeroed
#define QROWS 208     // q/k rows allocated+written (pad rows zeroed)
#define NH 8
#define KD 32
#define DHEAD 128
#define DH 1024
#define DIM 384
#define SCALE 0.17677669529663687f

__device__ __forceinline__ float b2f(bf16 v) { return __bfloat162float(v); }
__device__ __forceinline__ bf16 f2b(float f) { return __float2bfloat16(f); }
__device__ __forceinline__ float us2f(unsigned short u) {
  union { unsigned int i; float f; } v; v.i = (unsigned int)u << 16; return v.f;
}
__device__ __forceinline__ short f2us(float f) {
  bf16 b = __float2bfloat16(f);
  return *(short*)&b;
}

// CK-style global->LDS 16B async copy
__device__ __forceinline__ void gll16(const void* g, void* l) {
  auto gp = reinterpret_cast<const uint32_t __attribute__((address_space(1)))*>(
      reinterpret_cast<uintptr_t>(g));
  auto lp = reinterpret_cast<uint32_t __attribute__((address_space(3)))*>(
      reinterpret_cast<uintptr_t>(l));
  __builtin_amdgcn_global_load_lds(gp, lp, 16, 0, 0);
}

// ---------- fp32 -> bf16 weight conversion ----------
__global__ __launch_bounds__(256) void k_cvt(const float* __restrict__ src,
                                             bf16* __restrict__ dst, int n) {
  int i = blockIdx.x * 256 + threadIdx.x;
  if (i < n) dst[i] = f2b(src[i]);
}

// ---------- transpose x (B,384,196) fp32 -> XT (B,208,384) bf16, rows >=196 zeroed ----------
__global__ __launch_bounds__(256) void k_xt(const float* __restrict__ x,
                                            bf16* __restrict__ XT) {
  __shared__ bf16 tile[32][33];
  int ct = blockIdx.x, nt = blockIdx.y, b = blockIdx.z;
  int c0 = ct * 32, n0 = nt * 32;
  int tc = threadIdx.x >> 5, tn = threadIdx.x & 31;
#pragma unroll
  for (int r = 0; r < 4; ++r) {
    int c = tc + r * 8;
    int n = n0 + tn;
    float v = 0.f;
    if (n < NPIX) v = x[((size_t)b * DIM + c0 + c) * NPIX + n];
    tile[c][tn] = f2b(v);
  }
  __syncthreads();
#pragma unroll
  for (int r = 0; r < 4; ++r) {
    int n = n0 + tc + r * 8;
    if (n < NPAD) XT[((size_t)b * NPAD + n) * DIM + c0 + tn] = tile[tn][tc + r * 8];
  }
}

// ---------- fused QKV projection: LDS-staged 128x128 tile GEMM ----------
__global__ __launch_bounds__(256, 2) void k_qkv2(
    const bf16* __restrict__ Wf, const bf16* __restrict__ XT,
    const float* __restrict__ qb, const float* __restrict__ qs, const float* __restrict__ qt,
    const float* __restrict__ kb, const float* __restrict__ ks, const float* __restrict__ kt,
    const float* __restrict__ vb, const float* __restrict__ vs, const float* __restrict__ vt,
    bf16* __restrict__ qf, bf16* __restrict__ kf, bf16* __restrict__ v4) {
  __shared__ __align__(16) char lds[2][32768];  // [buf][A 16KB | B 16KB]
  const int NWG = 12 * 208;  // 2496, %8==0
  int id = blockIdx.x;
  int id2 = (id & 7) * (NWG >> 3) + (id >> 3);  // XCD-contiguous
  int mt = id2 % 12, nt = id2 / 12;
  int m0 = mt * 128, n0 = nt * 128;
  int tid = threadIdx.x, lane = tid & 63;
  int wv = tid >> 6, wm = wv >> 1, wn = wv & 1;

  f32x4 acc[4][4];
#pragma unroll
  for (int mi = 0; mi < 4; ++mi)
#pragma unroll
    for (int ni = 0; ni < 4; ++ni)
#pragma unroll
      for (int r = 0; r < 4; ++r) acc[mi][ni][r] = 0.f;

  auto stage = [&](int buf, int t) {
    int k0 = t * 64;
#pragma unroll
    for (int j = 0; j < 4; ++j) {
      int gi = tid + j * 256;
      int row = gi >> 3, g = gi & 7;
      int sk = k0 + ((g ^ (row & 7)) << 3);
      gll16(Wf + (size_t)(m0 + row) * DIM + sk, &lds[buf][gi * 16]);
      gll16(XT + (size_t)(n0 + row) * DIM + sk, &lds[buf][16384 + gi * 16]);
    }
  };
  auto compute = [&](int buf) {
    const char* Ab = lds[buf];
    const char* Bb = lds[buf] + 16384;
    int kq = lane >> 4, il = lane & 15;
#pragma unroll
    for (int ksb = 0; ksb < 2; ++ksb) {
      int G = ksb * 4 + kq;
      short8 af[4], bfr[4];
#pragma unroll
      for (int mi = 0; mi < 4; ++mi) {
        int row = wm * 64 + mi * 16 + il;
        af[mi] = *(const short8*)(Ab + row * 128 + ((G ^ (row & 7)) << 4));
      }
#pragma unroll
      for (int ni = 0; ni < 4; ++ni) {
        int row = wn * 64 + ni * 16 + il;
        bfr[ni] = *(const short8*)(Bb + row * 128 + ((G ^ (row & 7)) << 4));
      }
#pragma unroll
      for (int mi = 0; mi < 4; ++mi)
#pragma unroll
        for (int ni = 0; ni < 4; ++ni)
          acc[mi][ni] = __builtin_amdgcn_mfma_f32_16x16x32_bf16(af[mi], bfr[ni], acc[mi][ni], 0, 0, 0);
    }
  };

  stage(0, 0);
  __syncthreads();
  for (int t = 0; t < 6; ++t) {
    if (t < 5) stage((t + 1) & 1, t + 1);
    compute(t & 1);
    __syncthreads();
  }

  int cq = lane >> 4, cn = lane & 15;
#pragma unroll
  for (int mi = 0; mi < 4; ++mi) {
    int mbase = m0 + wm * 64 + mi * 16;
    const float *bp, *sp, *tp;
    int segbase, segid;
    if (mbase < 256)      { bp = qb; sp = qs; tp = qt; segbase = 0;   segid = 0; }
    else if (mbase < 512) { bp = kb; sp = ks; tp = kt; segbase = 256; segid = 1; }
    else                  { bp = vb; sp = vs; tp = vt; segbase = 512; segid = 2; }
#pragma unroll
    for (int r = 0; r < 4; ++r) {
      int ms = mbase - segbase + cq * 4 + r;
      float bi = bp[ms], sc = sp[ms], tt = tp[ms];
#pragma unroll
      for (int ni = 0; ni < 4; ++ni) {
        int n = n0 + wn * 64 + ni * 16 + cn;
        int b = n / NPAD;
        int nn = n - b * NPAD;
        float y = (acc[mi][ni][r] + bi) * sc + tt;
        y = (nn < NPIX) ? y : 0.f;
        if (segid == 2) {
          v4[((size_t)b * DH + ms) * VP + nn] = f2b(y);
        } else {
          bf16* dst = segid ? kf : qf;
          dst[(((size_t)b * NH + (ms >> 5)) * QROWS + nn) * KD + (ms & 31)] = f2b(y);
        }
      }
    }
  }
}

// ---------- zero v4 pad cols [208,224) ----------
__global__ __launch_bounds__(256) void k_vpad(bf16* __restrict__ v4) {
  int i = blockIdx.x * 256 + threadIdx.x;
  int tot = NB * DH * 16;
  if (i < tot) {
    int row = i >> 4, c = i & 15;
    v4[(size_t)row * VP + 208 + c] = f2b(0.f);
  }
}

// ---------- final projection: LDS-staged 128x128 tile GEMM, fp32 out ----------
__global__ __launch_bounds__(256, 2) void k_p2(
    const bf16* __restrict__ Pw, const bf16* __restrict__ OT,
    const float* __restrict__ pb, const float* __restrict__ ps, const float* __restrict__ pt,
    float* __restrict__ out) {
  __shared__ __align__(16) char lds[2][32768];
  const int NWG = 3 * 208;  // 624, %8==0
  int id = blockIdx.x;
  int id2 = (id & 7) * (NWG >> 3) + (id >> 3);
  int mt = id2 % 3, nt = id2 / 3;
  int m0 = mt * 128, n0 = nt * 128;
  int tid = threadIdx.x, lane = tid & 63;
  int wv = tid >> 6, wm = wv >> 1, wn = wv & 1;

  f32x4 acc[4][4];
#pragma unroll
  for (int mi = 0; mi < 4; ++mi)
#pragma unroll
    for (int ni = 0; ni < 4; ++ni)
#pragma unroll
      for (int r = 0; r < 4; ++r) acc[mi][ni][r] = 0.f;

  auto stage = [&](int buf, int t) {
    int k0 = t * 64;
#pragma unroll
    for (int j = 0; j < 4; ++j) {
      int gi = tid + j * 256;
      int row = gi >> 3, g = gi & 7;
      int sk = k0 + ((g ^ (row & 7)) << 3);
      gll16(Pw + (size_t)(m0 + row) * DH + sk, &lds[buf][gi * 16]);
      gll16(OT + (size_t)(n0 + row) * DH + sk, &lds[buf][16384 + gi * 16]);
    }
  };
  auto compute = [&](int buf) {
    const char* Ab = lds[buf];
    const char* Bb = lds[buf] + 16384;
    int kq = lane >> 4, il = lane & 15;
#pragma unroll
    for (int ksb = 0; ksb < 2; ++ksb) {
      int G = ksb * 4 + kq;
      short8 af[4], bfr[4];
#pragma unroll
      for (int mi = 0; mi < 4; ++mi) {
        int row = wm * 64 + mi * 16 + il;
        af[mi] = *(const short8*)(Ab + row * 128 + ((G ^ (row & 7)) << 4));
      }
#pragma unroll
      for (int ni = 0; ni < 4; ++ni) {
        int row = wn * 64 + ni * 16 + il;
        bfr[ni] = *(const short8*)(Bb + row * 128 + ((G ^ (row & 7)) << 4));
      }
#pragma unroll
      for (int mi = 0; mi < 4; ++mi)
#pragma unroll
        for (int ni = 0; ni < 4; ++ni)
          acc[mi][ni] = __builtin_amdgcn_mfma_f32_16x16x32_bf16(af[mi], bfr[ni], acc[mi][ni], 0, 0, 0);
    }
  };

  stage(0, 0);
  __syncthreads();
  for (int t = 0; t < 16; ++t) {
    if (t < 15) stage((t + 1) & 1, t + 1);
    compute(t & 1);
    __syncthreads();
  }

  int cq = lane >> 4, cn = lane & 15;
#pragma unroll
  for (int mi = 0; mi < 4; ++mi) {
#pragma unroll
    for (int r = 0; r < 4; ++r) {
      int m = m0 + wm * 64 + mi * 16 + cq * 4 + r;
      float bi = pb[m], sc = ps[m], tt = pt[m];
#pragma unroll
      for (int ni = 0; ni < 4; ++ni) {
        int n = n0 + wn * 64 + ni * 16 + cn;
        int b = n / NPAD;
        int nn = n - b * NPAD;
        if (nn < NPIX)
          out[((size_t)b * DIM + m) * NPIX + nn] = (acc[mi][ni][r] + bi) * sc + tt;
      }
    }
  }
}

// ---------- depthwise 3x3 + BN ----------
__global__ __launch_bounds__(256) void k_dw(
    const bf16* __restrict__ v4, const float* __restrict__ lvw,
    const float* __restrict__ lvb, const float* __restrict__ lvs,
    const float* __restrict__ lvt, bf16* __restrict__ vl) {
  int blk = blockIdx.x;
  int b = blk >> 8, cg = blk & 255;
  int lc = threadIdx.x >> 6, px = threadIdx.x & 63;
  int ch = cg * 4 + lc;
  const bf16* src = v4 + ((size_t)b * DH + ch) * VP;
  float w[9];
#pragma unroll
  for (int i = 0; i < 9; ++i) w[i] = lvw[ch * 9 + i];
  float bb = lvb[ch], ss = lvs[ch], tt = lvt[ch];
  bf16* dst = vl + ((size_t)b * DH + ch) * NPIX;
  for (int p = px; p < NPIX; p += 64) {
    int ri = p / 14, ci = p - ri * 14;
    float s = 0.f;
#pragma unroll
    for (int dy = -1; dy <= 1; ++dy)
#pragma unroll
      for (int dx = -1; dx <= 1; ++dx) {
        int rr = ri + dy, cc = ci + dx;
        if (rr >= 0 && rr < 14 && cc >= 0 && cc < 14)
          s += w[(dy + 1) * 3 + dx + 1] * b2f(src[rr * 14 + cc]);
      }
    dst[p] = f2b((s + bb) * ss + tt);
  }
}

// ---------- per-channel column sums of v (for the th2b term) ----------
__global__ __launch_bounds__(256) void k_vcs(const bf16* __restrict__ v4,
                                             float* __restrict__ vcs) {
  int b = blockIdx.x, g = blockIdx.y;
  int ch = g * 64 + (threadIdx.x >> 2);
  int part = threadIdx.x & 3;
  const bf16* src = v4 + ((size_t)b * DH + ch) * VP + part * 49;
  float s = 0.f;
  for (int j = 0; j < 49; ++j) s += b2f(src[j]);
  s += __shfl_xor(s, 1);
  s += __shfl_xor(s, 2);
  if (part == 0) vcs[b * DH + ch] = s;
}

// ---------- attention ----------
// S: bf16 [8 heads][16 rows][224 cols], row rotate-swizzled. 57344 B static LDS.
#define SROW 448  // bytes per S row
__device__ __forceinline__ int saddr(int g, int i, int j) {
  int r = j * 2 + ((i & 7) << 4);
  if (r >= SROW) r -= SROW;
  return (g * 16 + i) * SROW + r;
}

__global__ __launch_bounds__(512, 4) void k_att(
    const bf16* __restrict__ qf, const bf16* __restrict__ kf,
    const bf16* __restrict__ v4, const bf16* __restrict__ vl,
    const float* __restrict__ vcs,
    const float* __restrict__ th1w, const float* __restrict__ th1b,
    const float* __restrict__ th2w, const float* __restrict__ th2b,
    const float* __restrict__ ab, bf16* __restrict__ OT) {
  __shared__ __align__(16) char smem[NH * 16 * SROW];  // 57344 B
  __shared__ float ab2[NH * NPIX];                     // 6272 B
  __shared__ float c1s[64];
  __shared__ float c2s[64];
  __shared__ float smInv[NH * 16];                     // per-row 1/sum
  // batch->XCD affinity: all 13 Q-tiles of a batch share one XCD's L2.
  int id = blockIdx.x;            // 1664 linear
  int xcd = id & 7;
  int rest = id >> 3;             // [0,208)
  int qt = rest % 13;
  int b = (rest / 13) * 8 + xcd;  // [0,128), b%8 == xcd
  int i0 = qt * 16;
  int tid = threadIdx.x;
  int wave = tid >> 6, lane = tid & 63;
  int il = lane & 15, kh = lane >> 4;

  if (tid < 64) {
    c1s[tid] = th1w[tid] * SCALE;
    c2s[tid] = th2w[tid];
  }
  for (int pos = tid; pos < NH * NPIX; pos += 512) {
    int g = pos / NPIX, off = pos - g * NPIX;
    float s = th1b[g];
#pragma unroll
    for (int h = 0; h < 8; ++h)
      s += th1w[g * 8 + h] * ab[h * NPIX + off];
    ab2[pos] = s;
  }
  // ---- QK^T, head = wave; 16 q-rows x 208 k-rows, raw qk -> S (bf16) ----
  {
    const bf16* qp = qf + ((size_t)b * NH + wave) * QROWS * KD;
    const bf16* kp = kf + ((size_t)b * NH + wave) * QROWS * KD;
    short8 a = *(const short8*)(qp + (i0 + il) * KD + kh * 8);
    for (int jt = 0; jt < 13; ++jt) {
      short8 bb = *(const short8*)(kp + (jt * 16 + il) * KD + kh * 8);
      f32x4 acc = {0.f, 0.f, 0.f, 0.f};
      acc = __builtin_amdgcn_mfma_f32_16x16x32_bf16(a, bb, acc, 0, 0, 0);
      int j = jt * 16 + il;
#pragma unroll
      for (int r = 0; r < 4; ++r)
        *(bf16*)(smem + saddr(wave, kh * 4 + r, j)) = f2b(acc[r]);
    }
  }
  __syncthreads();
  // ---- pass A: talking-head-1 mix (with SCALE) + bias, 4-j vectorized ----
  for (int item = tid; item < 16 * 52; item += 512) {
    int i = item / 52, jq = item - i * 52;
    int j0 = jq * 4;
    float sv[8][4];
#pragma unroll
    for (int h = 0; h < 8; ++h) {
      short4v v = *(const short4v*)(smem + saddr(h, i, j0));
#pragma unroll
      for (int t = 0; t < 4; ++t) sv[h][t] = us2f((unsigned short)v[t]);
    }
    int ia = i0 + i; if (ia > 195) ia = 195;
    int ri = ia / 14, ci = ia - ri * 14;
    int off4[4];
    {
      int rj = j0 / 14, cj = j0 - rj * 14;
#pragma unroll
      for (int t = 0; t < 4; ++t) {
        if (cj >= 14) { cj -= 14; ++rj; }
        int dr = ri > rj ? ri - rj : rj - ri;
        int dc = ci > cj ? ci - cj : cj - ci;
        off4[t] = (j0 + t < NPIX) ? dr * 14 + dc : 0;
        ++cj;
      }
    }
#pragma unroll
    for (int g = 0; g < 8; ++g) {
      float o[4];
#pragma unroll
      for (int t = 0; t < 4; ++t) o[t] = ab2[g * NPIX + off4[t]];
#pragma unroll
      for (int h = 0; h < 8; ++h) {
        float c = c1s[g * 8 + h];
#pragma unroll
        for (int t = 0; t < 4; ++t) o[t] += c * sv[h][t];
      }
      short4v w;
#pragma unroll
      for (int t = 0; t < 4; ++t) w[t] = f2us(o[t]);
      *(short4v*)(smem + saddr(g, i, j0)) = w;
    }
  }
  __syncthreads();
  // ---- softmax: max pass + exp pass (stores unnormalized exp; inv -> smInv) ----
  {
    int row = tid >> 2, part = tid & 3;  // 128 rows = 8 heads x 16
    int g = row >> 4, i = row & 15;
    int jb = part * 52;
    int n4 = (part == 3) ? 10 : 13;  // part 3 covers j in [156,196)
    float m = -1e30f;
    for (int it = 0; it < n4; ++it) {
      short4v v = *(const short4v*)(smem + saddr(g, i, jb + it * 4));
#pragma unroll
      for (int t = 0; t < 4; ++t) m = fmaxf(m, us2f((unsigned short)v[t]));
    }
    m = fmaxf(m, __shfl_xor(m, 1));
    m = fmaxf(m, __shfl_xor(m, 2));
    float s = 0.f;
    for (int it = 0; it < n4; ++it) {
      char* p = smem + saddr(g, i, jb + it * 4);
      short4v v = *(const short4v*)p;
      short4v w;
#pragma unroll
      for (int t = 0; t < 4; ++t) {
        float e = __expf(us2f((unsigned short)v[t]) - m);
        s += e;
        w[t] = f2us(e);
      }
      *(short4v*)p = w;
    }
    if (part == 3) {  // zero pad cols [196,224)
      short4v z = {0, 0, 0, 0};
#pragma unroll
      for (int it = 0; it < 7; ++it)
        *(short4v*)(smem + saddr(g, i, 196 + it * 4)) = z;
    }
    s += __shfl_xor(s, 1);
    s += __shfl_xor(s, 2);
    if (part == 0) smInv[row] = 1.f / s;
  }
  __syncthreads();
  // ---- pass C: talking-head-2 mix with folded 1/sum, 4-j vectorized ----
  for (int item = tid; item < 16 * 49; item += 512) {
    int i = item / 49, jq = item - i * 49;
    int j0 = jq * 4;  // [0,196)
    float pv[8][4];
#pragma unroll
    for (int h = 0; h < 8; ++h) {
      float inv = smInv[h * 16 + i];
      short4v v = *(const short4v*)(smem + saddr(h, i, j0));
#pragma unroll
      for (int t = 0; t < 4; ++t) pv[h][t] = us2f((unsigned short)v[t]) * inv;
    }
#pragma unroll
    for (int g = 0; g < 8; ++g) {
      float o[4] = {0.f, 0.f, 0.f, 0.f};
#pragma unroll
      for (int h = 0; h < 8; ++h) {
        float c = c2s[g * 8 + h];
#pragma unroll
        for (int t = 0; t < 4; ++t) o[t] += c * pv[h][t];
      }
      short4v w;
#pragma unroll
      for (int t = 0; t < 4; ++t) w[t] = f2us(o[t]);
      *(short4v*)(smem + saddr(g, i, j0)) = w;
    }
  }
  __syncthreads();
  // ---- PV: O_g = P_g @ V_g^T, +th2b*colsum(v) +vl, relu, store transposed ----
  {
    int g = wave;
    f32x4 oacc[8];
#pragma unroll
    for (int dt = 0; dt < 8; ++dt)
#pragma unroll
      for (int r = 0; r < 4; ++r) oacc[dt][r] = 0.f;
    const bf16* vbase = v4 + ((size_t)b * DH + g * DHEAD) * VP;
    for (int ks = 0; ks < 7; ++ks) {
      short8 pa = *(const short8*)(smem + saddr(g, il, ks * 32 + kh * 8));
#pragma unroll
      for (int dt = 0; dt < 8; ++dt) {
        short8 bv = *(const short8*)(vbase + (size_t)(dt * 16 + il) * VP + ks * 32 + kh * 8);
        oacc[dt] = __builtin_amdgcn_mfma_f32_16x16x32_bf16(pa, bv, oacc[dt], 0, 0, 0);
      }
    }
    float t2b = th2b[g];
#pragma unroll
    for (int dt = 0; dt < 8; ++dt) {
      int ch = g * DHEAD + dt * 16 + il;
      float csv = vcs[b * DH + ch] * t2b;
#pragma unroll
      for (int r = 0; r < 4; ++r) {
        int n = i0 + kh * 4 + r;
        if (n < NPIX) {
          float val = oacc[dt][r] + csv + b2f(vl[((size_t)b * DH + ch) * NPIX + n]);
          OT[((size_t)b * NPAD + n) * DH + ch] = f2b(fmaxf(val, 0.f));
        } else {
          OT[((size_t)b * NPAD + n) * DH + ch] = f2b(0.f);
        }
      }
    }
  }
}

extern "C" void kernel_launch(void* const* d_in, const int* in_sizes, int n_in,
                              void* d_out, int out_size, void* d_ws, size_t ws_size,
                              hipStream_t stream) {
  const float* x    = (const float*)d_in[0];
  const float* qw   = (const float*)d_in[1];
  const float* qb   = (const float*)d_in[2];
  const float* q_s  = (const float*)d_in[3];
  const float* q_t  = (const float*)d_in[4];
  const float* kw   = (const float*)d_in[5];
  const float* kb   = (const float*)d_in[6];
  const float* k_s  = (const float*)d_in[7];
  const float* k_t  = (const float*)d_in[8];
  const float* vw   = (const float*)d_in[9];
  const float* vb   = (const float*)d_in[10];
  const float* v_s  = (const float*)d_in[11];
  const float* v_t  = (const float*)d_in[12];
  const float* lvw  = (const float*)d_in[13];
  const float* lvb  = (const float*)d_in[14];
  const float* lv_s = (const float*)d_in[15];
  const float* lv_t = (const float*)d_in[16];
  const float* th1w = (const float*)d_in[17];
  const float* th1b = (const float*)d_in[18];
  const float* th2w = (const float*)d_in[19];
  const float* th2b = (const float*)d_in[20];
  const float* ab   = (const float*)d_in[21];
  const float* pw   = (const float*)d_in[22];
  const float* pb   = (const float*)d_in[23];
  const float* p_s  = (const float*)d_in[24];
  const float* p_t  = (const float*)d_in[25];

  char* ws = (char*)d_ws;
  size_t off = 0;
  auto alloc = [&](size_t bytes) {
    char* p = ws + off;
    off += (bytes + 255) & ~(size_t)255;
    return p;
  };
  // region0: XT (B,208,384 bf16) aliased with OT (B,208,1024 bf16)
  char* region0 = alloc((size_t)NB * NPAD * DH * 2);
  bf16* XT  = (bf16*)region0;
  bf16* OT  = (bf16*)region0;
  bf16* qfb = (bf16*)alloc((size_t)NB * NH * QROWS * KD * 2);
  bf16* kfb = (bf16*)alloc((size_t)NB * NH * QROWS * KD * 2);
  bf16* v4  = (bf16*)alloc((size_t)NB * DH * VP * 2);
  bf16* vlb = (bf16*)alloc((size_t)NB * DH * NPIX * 2);
  float* vcs = (float*)alloc((size_t)NB * DH * 4);
  bf16* wf  = (bf16*)alloc((size_t)1536 * DIM * 2);  // fused Q|K|V weights
  bf16* wpb = (bf16*)alloc((size_t)DIM * DH * 2);
  (void)ws_size; (void)in_sizes; (void)n_in; (void)out_size;

  k_cvt<<<dim3((256 * DIM + 255) / 256), 256, 0, stream>>>(qw, wf, 256 * DIM);
  k_cvt<<<dim3((256 * DIM + 255) / 256), 256, 0, stream>>>(kw, wf + 256 * DIM, 256 * DIM);
  k_cvt<<<dim3((DH * DIM + 255) / 256), 256, 0, stream>>>(vw, wf + 512 * DIM, DH * DIM);
  k_cvt<<<dim3((DIM * DH + 255) / 256), 256, 0, stream>>>(pw, wpb, DIM * DH);
  k_xt<<<dim3(12, 7, NB), 256, 0, stream>>>(x, XT);
  k_qkv2<<<dim3(2496), 256, 0, stream>>>(wf, XT, qb, q_s, q_t, kb, k_s, k_t,
                                         vb, v_s, v_t, qfb, kfb, v4);
  k_vpad<<<dim3((NB * DH * 16 + 255) / 256), 256, 0, stream>>>(v4);
  k_dw<<<dim3(NB * 256), 256, 0, stream>>>(v4, lvw, lvb, lv_s, lv_t, vlb);
  k_vcs<<<dim3(NB, 16), 256, 0, stream>>>(v4, vcs);
  k_att<<<dim3(1664), 512, 0, stream>>>(qfb, kfb, v4, vlb, vcs,
                                        th1w, th1b, th2w, th2b, ab, OT);
  k_p2<<<dim3(624), 256, 0, stream>>>(wpb, OT, pb, p_s, p_t, (float*)d_out);
}

// Round 7
// 493.266 us; speedup vs baseline: 1.2002x; 1.2002x over previous
//
#include <hip/hip_runtime.h>
#include <hip/hip_bf16.h>
#include <stdint.h>

typedef __hip_bfloat16 bf16;
typedef short short8 __attribute__((ext_vector_type(8)));
typedef float f32x4 __attribute__((ext_vector_type(4)));

#define NB 128
#define NPIX 196      // 14*14
#define NPAD 208      // 13*16
#define VP 224        // v4 row pitch (7*32 for PV k-steps), cols [208,224) zeroed
#define QROWS 208     // q/k rows allocated+written (pad rows zeroed)
#define NH 8
#define KD 32
#define DHEAD 128
#define DH 1024
#define DIM 384
#define SCALE 0.17677669529663687f

__device__ __forceinline__ float b2f(bf16 v) { return __bfloat162float(v); }
__device__ __forceinline__ bf16 f2b(float f) { return __float2bfloat16(f); }
__device__ __forceinline__ float us2f(unsigned short u) {
  union { unsigned int i; float f; } v; v.i = (unsigned int)u << 16; return v.f;
}
__device__ __forceinline__ short f2us(float f) {
  bf16 b = __float2bfloat16(f);
  return *(short*)&b;
}

// CK-style global->LDS 16B async copy
__device__ __forceinline__ void gll16(const void* g, void* l) {
  auto gp = reinterpret_cast<const uint32_t __attribute__((address_space(1)))*>(
      reinterpret_cast<uintptr_t>(g));
  auto lp = reinterpret_cast<uint32_t __attribute__((address_space(3)))*>(
      reinterpret_cast<uintptr_t>(l));
  __builtin_amdgcn_global_load_lds(gp, lp, 16, 0, 0);
}

// ---------- fp32 -> bf16 weight conversion, all 4 weight mats in one launch ----------
// dst is wf (1536*384) immediately followed by wpb (384*1024) in ws.
__global__ __launch_bounds__(256) void k_cvt4(const float* __restrict__ s0,
                                              const float* __restrict__ s1,
                                              const float* __restrict__ s2,
                                              const float* __restrict__ s3,
                                              bf16* __restrict__ dst) {
  int i = blockIdx.x * 256 + threadIdx.x;
  if (i >= 983040) return;
  const float* src; int o;
  if (i < 98304)       { src = s0; o = i; }
  else if (i < 196608) { src = s1; o = i - 98304; }
  else if (i < 589824) { src = s2; o = i - 196608; }
  else                 { src = s3; o = i - 589824; }
  dst[i] = f2b(src[o]);
}

// ---------- transpose x (B,384,196) fp32 -> XT (B,208,384) bf16, rows >=196 zeroed ----------
__global__ __launch_bounds__(256) void k_xt(const float* __restrict__ x,
                                            bf16* __restrict__ XT) {
  __shared__ bf16 tile[32][33];
  int ct = blockIdx.x, nt = blockIdx.y, b = blockIdx.z;
  int c0 = ct * 32, n0 = nt * 32;
  int tc = threadIdx.x >> 5, tn = threadIdx.x & 31;
#pragma unroll
  for (int r = 0; r < 4; ++r) {
    int c = tc + r * 8;
    int n = n0 + tn;
    float v = 0.f;
    if (n < NPIX) v = x[((size_t)b * DIM + c0 + c) * NPIX + n];
    tile[c][tn] = f2b(v);
  }
  __syncthreads();
#pragma unroll
  for (int r = 0; r < 4; ++r) {
    int n = n0 + tc + r * 8;
    if (n < NPAD) XT[((size_t)b * NPAD + n) * DIM + c0 + tn] = tile[tn][tc + r * 8];
  }
}

// ---------- fused QKV projection: LDS-staged 128x128 tile GEMM ----------
__global__ __launch_bounds__(256, 2) void k_qkv2(
    const bf16* __restrict__ Wf, const bf16* __restrict__ XT,
    const float* __restrict__ qb, const float* __restrict__ qs, const float* __restrict__ qt,
    const float* __restrict__ kb, const float* __restrict__ ks, const float* __restrict__ kt,
    const float* __restrict__ vb, const float* __restrict__ vs, const float* __restrict__ vt,
    bf16* __restrict__ qf, bf16* __restrict__ kf, bf16* __restrict__ v4) {
  __shared__ __align__(16) char lds[2][32768];  // [buf][A 16KB | B 16KB]
  const int NWG = 12 * 208;  // 2496, %8==0
  int id = blockIdx.x;
  int id2 = (id & 7) * (NWG >> 3) + (id >> 3);  // XCD-contiguous
  int mt = id2 % 12, nt = id2 / 12;
  int m0 = mt * 128, n0 = nt * 128;
  int tid = threadIdx.x, lane = tid & 63;
  int wv = tid >> 6, wm = wv >> 1, wn = wv & 1;

  f32x4 acc[4][4];
#pragma unroll
  for (int mi = 0; mi < 4; ++mi)
#pragma unroll
    for (int ni = 0; ni < 4; ++ni)
#pragma unroll
      for (int r = 0; r < 4; ++r) acc[mi][ni][r] = 0.f;

  auto stage = [&](int buf, int t) {
    int k0 = t * 64;
#pragma unroll
    for (int j = 0; j < 4; ++j) {
      int gi = tid + j * 256;
      int row = gi >> 3, g = gi & 7;
      int sk = k0 + ((g ^ (row & 7)) << 3);
      gll16(Wf + (size_t)(m0 + row) * DIM + sk, &lds[buf][gi * 16]);
      gll16(XT + (size_t)(n0 + row) * DIM + sk, &lds[buf][16384 + gi * 16]);
    }
  };
  auto compute = [&](int buf) {
    const char* Ab = lds[buf];
    const char* Bb = lds[buf] + 16384;
    int kq = lane >> 4, il = lane & 15;
#pragma unroll
    for (int ksb = 0; ksb < 2; ++ksb) {
      int G = ksb * 4 + kq;
      short8 af[4], bfr[4];
#pragma unroll
      for (int mi = 0; mi < 4; ++mi) {
        int row = wm * 64 + mi * 16 + il;
        af[mi] = *(const short8*)(Ab + row * 128 + ((G ^ (row & 7)) << 4));
      }
#pragma unroll
      for (int ni = 0; ni < 4; ++ni) {
        int row = wn * 64 + ni * 16 + il;
        bfr[ni] = *(const short8*)(Bb + row * 128 + ((G ^ (row & 7)) << 4));
      }
#pragma unroll
      for (int mi = 0; mi < 4; ++mi)
#pragma unroll
        for (int ni = 0; ni < 4; ++ni)
          acc[mi][ni] = __builtin_amdgcn_mfma_f32_16x16x32_bf16(af[mi], bfr[ni], acc[mi][ni], 0, 0, 0);
    }
  };

  stage(0, 0);
  __syncthreads();
  for (int t = 0; t < 6; ++t) {
    if (t < 5) stage((t + 1) & 1, t + 1);
    compute(t & 1);
    __syncthreads();
  }

  int cq = lane >> 4, cn = lane & 15;
#pragma unroll
  for (int mi = 0; mi < 4; ++mi) {
    int mbase = m0 + wm * 64 + mi * 16;
    const float *bp, *sp, *tp;
    int segbase, segid;
    if (mbase < 256)      { bp = qb; sp = qs; tp = qt; segbase = 0;   segid = 0; }
    else if (mbase < 512) { bp = kb; sp = ks; tp = kt; segbase = 256; segid = 1; }
    else                  { bp = vb; sp = vs; tp = vt; segbase = 512; segid = 2; }
#pragma unroll
    for (int r = 0; r < 4; ++r) {
      int ms = mbase - segbase + cq * 4 + r;
      float bi = bp[ms], sc = sp[ms], tt = tp[ms];
#pragma unroll
      for (int ni = 0; ni < 4; ++ni) {
        int n = n0 + wn * 64 + ni * 16 + cn;
        int b = n / NPAD;
        int nn = n - b * NPAD;
        float y = (acc[mi][ni][r] + bi) * sc + tt;
        y = (nn < NPIX) ? y : 0.f;
        if (segid == 2) {
          v4[((size_t)b * DH + ms) * VP + nn] = f2b(y);
        } else {
          bf16* dst = segid ? kf : qf;
          dst[(((size_t)b * NH + (ms >> 5)) * QROWS + nn) * KD + (ms & 31)] = f2b(y);
        }
      }
    }
  }
}

// ---------- zero v4 pad cols [208,224) ----------
__global__ __launch_bounds__(256) void k_vpad(bf16* __restrict__ v4) {
  int i = blockIdx.x * 256 + threadIdx.x;
  int tot = NB * DH * 16;
  if (i < tot) {
    int row = i >> 4, c = i & 15;
    v4[(size_t)row * VP + 208 + c] = f2b(0.f);
  }
}

// ---------- final projection: LDS-staged 128x128 tile GEMM, fp32 out ----------
__global__ __launch_bounds__(256, 2) void k_p2(
    const bf16* __restrict__ Pw, const bf16* __restrict__ OT,
    const float* __restrict__ pb, const float* __restrict__ ps, const float* __restrict__ pt,
    float* __restrict__ out) {
  __shared__ __align__(16) char lds[2][32768];
  const int NWG = 3 * 208;  // 624, %8==0
  int id = blockIdx.x;
  int id2 = (id & 7) * (NWG >> 3) + (id >> 3);
  int mt = id2 % 3, nt = id2 / 3;
  int m0 = mt * 128, n0 = nt * 128;
  int tid = threadIdx.x, lane = tid & 63;
  int wv = tid >> 6, wm = wv >> 1, wn = wv & 1;

  f32x4 acc[4][4];
#pragma unroll
  for (int mi = 0; mi < 4; ++mi)
#pragma unroll
    for (int ni = 0; ni < 4; ++ni)
#pragma unroll
      for (int r = 0; r < 4; ++r) acc[mi][ni][r] = 0.f;

  auto stage = [&](int buf, int t) {
    int k0 = t * 64;
#pragma unroll
    for (int j = 0; j < 4; ++j) {
      int gi = tid + j * 256;
      int row = gi >> 3, g = gi & 7;
      int sk = k0 + ((g ^ (row & 7)) << 3);
      gll16(Pw + (size_t)(m0 + row) * DH + sk, &lds[buf][gi * 16]);
      gll16(OT + (size_t)(n0 + row) * DH + sk, &lds[buf][16384 + gi * 16]);
    }
  };
  auto compute = [&](int buf) {
    const char* Ab = lds[buf];
    const char* Bb = lds[buf] + 16384;
    int kq = lane >> 4, il = lane & 15;
#pragma unroll
    for (int ksb = 0; ksb < 2; ++ksb) {
      int G = ksb * 4 + kq;
      short8 af[4], bfr[4];
#pragma unroll
      for (int mi = 0; mi < 4; ++mi) {
        int row = wm * 64 + mi * 16 + il;
        af[mi] = *(const short8*)(Ab + row * 128 + ((G ^ (row & 7)) << 4));
      }
#pragma unroll
      for (int ni = 0; ni < 4; ++ni) {
        int row = wn * 64 + ni * 16 + il;
        bfr[ni] = *(const short8*)(Bb + row * 128 + ((G ^ (row & 7)) << 4));
      }
#pragma unroll
      for (int mi = 0; mi < 4; ++mi)
#pragma unroll
        for (int ni = 0; ni < 4; ++ni)
          acc[mi][ni] = __builtin_amdgcn_mfma_f32_16x16x32_bf16(af[mi], bfr[ni], acc[mi][ni], 0, 0, 0);
    }
  };

  stage(0, 0);
  __syncthreads();
  for (int t = 0; t < 16; ++t) {
    if (t < 15) stage((t + 1) & 1, t + 1);
    compute(t & 1);
    __syncthreads();
  }

  int cq = lane >> 4, cn = lane & 15;
#pragma unroll
  for (int mi = 0; mi < 4; ++mi) {
#pragma unroll
    for (int r = 0; r < 4; ++r) {
      int m = m0 + wm * 64 + mi * 16 + cq * 4 + r;
      float bi = pb[m], sc = ps[m], tt = pt[m];
#pragma unroll
      for (int ni = 0; ni < 4; ++ni) {
        int n = n0 + wn * 64 + ni * 16 + cn;
        int b = n / NPAD;
        int nn = n - b * NPAD;
        if (nn < NPIX)
          out[((size_t)b * DIM + m) * NPIX + nn] = (acc[mi][ni][r] + bi) * sc + tt;
      }
    }
  }
}

// ---------- depthwise 3x3 + BN, fused with per-channel column sums ----------
__global__ __launch_bounds__(256) void k_dwv(
    const bf16* __restrict__ v4, const float* __restrict__ lvw,
    const float* __restrict__ lvb, const float* __restrict__ lvs,
    const float* __restrict__ lvt, bf16* __restrict__ vl,
    float* __restrict__ vcs) {
  int blk = blockIdx.x;
  int b = blk >> 8, cg = blk & 255;
  int lc = threadIdx.x >> 6, px = threadIdx.x & 63;
  int ch = cg * 4 + lc;
  const bf16* src = v4 + ((size_t)b * DH + ch) * VP;
  float w[9];
#pragma unroll
  for (int i = 0; i < 9; ++i) w[i] = lvw[ch * 9 + i];
  float bb = lvb[ch], ss = lvs[ch], tt = lvt[ch];
  bf16* dst = vl + ((size_t)b * DH + ch) * NPIX;
  float csum = 0.f;
  for (int p = px; p < NPIX; p += 64) {
    int ri = p / 14, ci = p - ri * 14;
    float s = 0.f;
#pragma unroll
    for (int dy = -1; dy <= 1; ++dy)
#pragma unroll
      for (int dx = -1; dx <= 1; ++dx) {
        int rr = ri + dy, cc = ci + dx;
        if (rr >= 0 && rr < 14 && cc >= 0 && cc < 14)
          s += w[(dy + 1) * 3 + dx + 1] * b2f(src[rr * 14 + cc]);
      }
    csum += b2f(src[p]);
    dst[p] = f2b((s + bb) * ss + tt);
  }
  // wave-wide (64-lane) reduction; one wave per channel
  csum += __shfl_xor(csum, 1);
  csum += __shfl_xor(csum, 2);
  csum += __shfl_xor(csum, 4);
  csum += __shfl_xor(csum, 8);
  csum += __shfl_xor(csum, 16);
  csum += __shfl_xor(csum, 32);
  if (px == 0) vcs[b * DH + ch] = csum;
}

// ---------- attention ----------
// S: bf16 [8 heads][16 rows][224 cols], row rotate-swizzled. 57344 B static LDS.
#define SROW 448  // bytes per S row
__device__ __forceinline__ int saddr(int g, int i, int j) {
  int r = j * 2 + ((i & 7) << 4);
  if (r >= SROW) r -= SROW;
  return (g * 16 + i) * SROW + r;
}

__global__ __launch_bounds__(512, 2) void k_att(
    const bf16* __restrict__ qf, const bf16* __restrict__ kf,
    const bf16* __restrict__ v4, const bf16* __restrict__ vl,
    const float* __restrict__ vcs,
    const float* __restrict__ th1w, const float* __restrict__ th1b,
    const float* __restrict__ th2w, const float* __restrict__ th2b,
    const float* __restrict__ ab, bf16* __restrict__ OT) {
  __shared__ __align__(16) char smem[NH * 16 * SROW];  // 57344 B
  __shared__ float ab2[NH * NPIX];                     // 6272 B
  __shared__ float c2s[64];
  // batch->XCD affinity: all 13 Q-tiles of a batch share one XCD's L2.
  int id = blockIdx.x;            // 1664 linear
  int xcd = id & 7;
  int rest = id >> 3;             // [0,208)
  int qt = rest % 13;
  int b = (rest / 13) * 8 + xcd;  // [0,128), b%8 == xcd
  int i0 = qt * 16;
  int tid = threadIdx.x;
  int wave = tid >> 6, lane = tid & 63;
  int il = lane & 15, kh = lane >> 4;

  if (tid < 64) c2s[tid] = th2w[tid];
  for (int pos = tid; pos < NH * NPIX; pos += 512) {
    int g = pos / NPIX, off = pos - g * NPIX;
    float s = th1b[g];
#pragma unroll
    for (int h = 0; h < 8; ++h)
      s += th1w[g * 8 + h] * ab[h * NPIX + off];
    ab2[pos] = s;
  }
  __syncthreads();  // ab2 ready for the QK' epilogue
  // ---- fused QK'^T: S'_g = sum_h (c1[g,h]*q_h) @ k_h^T + ab2  (K=256 concat GEMM) ----
  {
    const bf16* qpb = qf + (size_t)b * NH * QROWS * KD + (size_t)(i0 + il) * KD + kh * 8;
    const bf16* kpb = kf + (size_t)b * NH * QROWS * KD + (size_t)il * KD + kh * 8;
    short8 qfr[8];
#pragma unroll
    for (int h = 0; h < 8; ++h) {
      short8 raw = *(const short8*)(qpb + (size_t)h * QROWS * KD);
      float c = th1w[wave * 8 + h] * SCALE;
      short8 s;
#pragma unroll
      for (int e = 0; e < 8; ++e) s[e] = f2us(us2f((unsigned short)raw[e]) * c);
      qfr[h] = s;
    }
    int ri4[4], ci4[4];
#pragma unroll
    for (int r = 0; r < 4; ++r) {
      int ia = i0 + kh * 4 + r; if (ia > 195) ia = 195;
      int rr = (ia * 4682) >> 16;
      ri4[r] = rr; ci4[r] = ia - rr * 14;
    }
    for (int jt = 0; jt < 13; ++jt) {
      f32x4 a0 = {0.f, 0.f, 0.f, 0.f};
      f32x4 a1 = {0.f, 0.f, 0.f, 0.f};
#pragma unroll
      for (int h = 0; h < 8; h += 2) {
        short8 b0 = *(const short8*)(kpb + (size_t)h * QROWS * KD + jt * 16 * KD);
        short8 b1 = *(const short8*)(kpb + (size_t)(h + 1) * QROWS * KD + jt * 16 * KD);
        a0 = __builtin_amdgcn_mfma_f32_16x16x32_bf16(qfr[h], b0, a0, 0, 0, 0);
        a1 = __builtin_amdgcn_mfma_f32_16x16x32_bf16(qfr[h + 1], b1, a1, 0, 0, 0);
      }
      int j = jt * 16 + il;
      int rj = (j * 4682) >> 16;
      int cj = j - rj * 14;
#pragma unroll
      for (int r = 0; r < 4; ++r) {
        int dr = ri4[r] > rj ? ri4[r] - rj : rj - ri4[r];
        int dc = ci4[r] > cj ? ci4[r] - cj : cj - ci4[r];
        int off = (j < NPIX) ? dr * 14 + dc : 0;
        float v = a0[r] + a1[r] + ab2[wave * NPIX + off];
        *(bf16*)(smem + saddr(wave, kh * 4 + r, j)) = f2b(v);
      }
    }
  }
  __syncthreads();
  // ---- softmax over j (4 threads per (g,i) row), zero pad cols ----
  {
    int row = tid >> 2, part = tid & 3;  // 128 rows = 8 heads x 16
    int g = row >> 4, i = row & 15;
    int jb = part * 49, je = jb + 49;
    float m = -1e30f;
    for (int j = jb; j < je; ++j)
      m = fmaxf(m, b2f(*(const bf16*)(smem + saddr(g, i, j))));
    m = fmaxf(m, __shfl_xor(m, 1));
    m = fmaxf(m, __shfl_xor(m, 2));
    float s = 0.f;
    for (int j = jb; j < je; ++j)
      s += __expf(b2f(*(const bf16*)(smem + saddr(g, i, j))) - m);
    s += __shfl_xor(s, 1);
    s += __shfl_xor(s, 2);
    float inv = 1.f / s;
    for (int j = jb; j < je; ++j) {
      bf16* p = (bf16*)(smem + saddr(g, i, j));
      *p = f2b(__expf(b2f(*p) - m) * inv);
    }
    if (part == 3)
      for (int j = NPIX; j < VP; ++j)
        *(bf16*)(smem + saddr(g, i, j)) = f2b(0.f);
  }
  __syncthreads();
  // ---- pass C: talking-head-2 mix ----
  for (int pos = tid; pos < 16 * NPIX; pos += 512) {
    int i = pos / NPIX, j = pos - i * NPIX;
    float pv[8];
#pragma unroll
    for (int g = 0; g < 8; ++g) pv[g] = b2f(*(const bf16*)(smem + saddr(g, i, j)));
#pragma unroll
    for (int g2 = 0; g2 < 8; ++g2) {
      float s = 0.f;
#pragma unroll
      for (int g = 0; g < 8; ++g) s += c2s[g2 * 8 + g] * pv[g];
      *(bf16*)(smem + saddr(g2, i, j)) = f2b(s);
    }
  }
  __syncthreads();
  // ---- PV: O_g = P_g @ V_g^T, +th2b*colsum(v) +vl, relu, store transposed ----
  {
    int g = wave;
    f32x4 oacc[8];
#pragma unroll
    for (int dt = 0; dt < 8; ++dt)
#pragma unroll
      for (int r = 0; r < 4; ++r) oacc[dt][r] = 0.f;
    const bf16* vbase = v4 + ((size_t)b * DH + g * DHEAD) * VP;
    for (int ks = 0; ks < 7; ++ks) {
      short8 pa = *(const short8*)(smem + saddr(g, il, ks * 32 + kh * 8));
#pragma unroll
      for (int dt = 0; dt < 8; ++dt) {
        short8 bv = *(const short8*)(vbase + (size_t)(dt * 16 + il) * VP + ks * 32 + kh * 8);
        oacc[dt] = __builtin_amdgcn_mfma_f32_16x16x32_bf16(pa, bv, oacc[dt], 0, 0, 0);
      }
    }
    float t2b = th2b[g];
#pragma unroll
    for (int dt = 0; dt < 8; ++dt) {
      int ch = g * DHEAD + dt * 16 + il;
      float csv = vcs[b * DH + ch] * t2b;
#pragma unroll
      for (int r = 0; r < 4; ++r) {
        int n = i0 + kh * 4 + r;
        if (n < NPIX) {
          float val = oacc[dt][r] + csv + b2f(vl[((size_t)b * DH + ch) * NPIX + n]);
          OT[((size_t)b * NPAD + n) * DH + ch] = f2b(fmaxf(val, 0.f));
        } else {
          OT[((size_t)b * NPAD + n) * DH + ch] = f2b(0.f);
        }
      }
    }
  }
}

extern "C" void kernel_launch(void* const* d_in, const int* in_sizes, int n_in,
                              void* d_out, int out_size, void* d_ws, size_t ws_size,
                              hipStream_t stream) {
  const float* x    = (const float*)d_in[0];
  const float* qw   = (const float*)d_in[1];
  const float* qb   = (const float*)d_in[2];
  const float* q_s  = (const float*)d_in[3];
  const float* q_t  = (const float*)d_in[4];
  const float* kw   = (const float*)d_in[5];
  const float* kb   = (const float*)d_in[6];
  const float* k_s  = (const float*)d_in[7];
  const float* k_t  = (const float*)d_in[8];
  const float* vw   = (const float*)d_in[9];
  const float* vb   = (const float*)d_in[10];
  const float* v_s  = (const float*)d_in[11];
  const float* v_t  = (const float*)d_in[12];
  const float* lvw  = (const float*)d_in[13];
  const float* lvb  = (const float*)d_in[14];
  const float* lv_s = (const float*)d_in[15];
  const float* lv_t = (const float*)d_in[16];
  const float* th1w = (const float*)d_in[17];
  const float* th1b = (const float*)d_in[18];
  const float* th2w = (const float*)d_in[19];
  const float* th2b = (const float*)d_in[20];
  const float* ab   = (const float*)d_in[21];
  const float* pw   = (const float*)d_in[22];
  const float* pb   = (const float*)d_in[23];
  const float* p_s  = (const float*)d_in[24];
  const float* p_t  = (const float*)d_in[25];

  char* ws = (char*)d_ws;
  size_t off = 0;
  auto alloc = [&](size_t bytes) {
    char* p = ws + off;
    off += (bytes + 255) & ~(size_t)255;
    return p;
  };
  // region0: XT (B,208,384 bf16) aliased with OT (B,208,1024 bf16)
  char* region0 = alloc((size_t)NB * NPAD * DH * 2);
  bf16* XT  = (bf16*)region0;
  bf16* OT  = (bf16*)region0;
  bf16* qfb = (bf16*)alloc((size_t)NB * NH * QROWS * KD * 2);
  bf16* kfb = (bf16*)alloc((size_t)NB * NH * QROWS * KD * 2);
  bf16* v4  = (bf16*)alloc((size_t)NB * DH * VP * 2);
  bf16* vlb = (bf16*)alloc((size_t)NB * DH * NPIX * 2);
  float* vcs = (float*)alloc((size_t)NB * DH * 4);
  bf16* wf  = (bf16*)alloc((size_t)1536 * DIM * 2);  // fused Q|K|V weights (1179648 B, 256-aligned)
  bf16* wpb = (bf16*)alloc((size_t)DIM * DH * 2);    // immediately follows wf
  (void)ws_size; (void)in_sizes; (void)n_in; (void)out_size;

  k_cvt4<<<dim3(3840), 256, 0, stream>>>(qw, kw, vw, pw, wf);
  k_xt<<<dim3(12, 7, NB), 256, 0, stream>>>(x, XT);
  k_qkv2<<<dim3(2496), 256, 0, stream>>>(wf, XT, qb, q_s, q_t, kb, k_s, k_t,
                                         vb, v_s, v_t, qfb, kfb, v4);
  k_vpad<<<dim3((NB * DH * 16 + 255) / 256), 256, 0, stream>>>(v4);
  k_dwv<<<dim3(NB * 256), 256, 0, stream>>>(v4, lvw, lvb, lv_s, lv_t, vlb, vcs);
  k_att<<<dim3(1664), 512, 0, stream>>>(qfb, kfb, v4, vlb, vcs,
                                        th1w, th1b, th2w, th2b, ab, OT);
  k_p2<<<dim3(624), 256, 0, stream>>>(wpb, OT, pb, p_s, p_t, (float*)d_out);
}

// Round 8
// 437.111 us; speedup vs baseline: 1.3543x; 1.1285x over previous
//
#include <hip/hip_runtime.h>
#include <hip/hip_bf16.h>
#include <stdint.h>

typedef __hip_bfloat16 bf16;
typedef short short4v __attribute__((ext_vector_type(4)));
typedef short short8 __attribute__((ext_vector_type(8)));
typedef float f32x4 __attribute__((ext_vector_type(4)));

#define NB 128
#define NPIX 196      // 14*14
#define NPAD 208      // 13*16
#define VP 224        // v4 row pitch (7*32 for PV k-steps), cols [208,224) zeroed
#define QROWS 208     // q/k rows allocated+written (pad rows zeroed)
#define NH 8
#define KD 32
#define DHEAD 128
#define DH 1024
#define DIM 384
#define SCALE 0.17677669529663687f

__device__ __forceinline__ float b2f(bf16 v) { return __bfloat162float(v); }
__device__ __forceinline__ bf16 f2b(float f) { return __float2bfloat16(f); }
__device__ __forceinline__ float us2f(unsigned short u) {
  union { unsigned int i; float f; } v; v.i = (unsigned int)u << 16; return v.f;
}
__device__ __forceinline__ short f2us(float f) {
  bf16 b = __float2bfloat16(f);
  return *(short*)&b;
}

// CK-style global->LDS 16B async copy
__device__ __forceinline__ void gll16(const void* g, void* l) {
  auto gp = reinterpret_cast<const uint32_t __attribute__((address_space(1)))*>(
      reinterpret_cast<uintptr_t>(g));
  auto lp = reinterpret_cast<uint32_t __attribute__((address_space(3)))*>(
      reinterpret_cast<uintptr_t>(l));
  __builtin_amdgcn_global_load_lds(gp, lp, 16, 0, 0);
}

// ---------- fp32 -> bf16 weight conversion, all 4 weight mats in one launch ----------
__global__ __launch_bounds__(256) void k_cvt4(const float* __restrict__ s0,
                                              const float* __restrict__ s1,
                                              const float* __restrict__ s2,
                                              const float* __restrict__ s3,
                                              bf16* __restrict__ dst) {
  int i = blockIdx.x * 256 + threadIdx.x;
  if (i >= 983040) return;
  const float* src; int o;
  if (i < 98304)       { src = s0; o = i; }
  else if (i < 196608) { src = s1; o = i - 98304; }
  else if (i < 589824) { src = s2; o = i - 196608; }
  else                 { src = s3; o = i - 589824; }
  dst[i] = f2b(src[o]);
}

// ---------- transpose x (B,384,196) fp32 -> XT (B,208,384) bf16, rows >=196 zeroed ----------
__global__ __launch_bounds__(256) void k_xt(const float* __restrict__ x,
                                            bf16* __restrict__ XT) {
  __shared__ bf16 tile[32][33];
  int ct = blockIdx.x, nt = blockIdx.y, b = blockIdx.z;
  int c0 = ct * 32, n0 = nt * 32;
  int tc = threadIdx.x >> 5, tn = threadIdx.x & 31;
#pragma unroll
  for (int r = 0; r < 4; ++r) {
    int c = tc + r * 8;
    int n = n0 + tn;
    float v = 0.f;
    if (n < NPIX) v = x[((size_t)b * DIM + c0 + c) * NPIX + n];
    tile[c][tn] = f2b(v);
  }
  __syncthreads();
#pragma unroll
  for (int r = 0; r < 4; ++r) {
    int n = n0 + tc + r * 8;
    if (n < NPAD) XT[((size_t)b * NPAD + n) * DIM + c0 + tn] = tile[tn][tc + r * 8];
  }
}

// ---------- fused QKV projection: LDS-staged 128x128 tile GEMM ----------
__global__ __launch_bounds__(256, 2) void k_qkv2(
    const bf16* __restrict__ Wf, const bf16* __restrict__ XT,
    const float* __restrict__ qb, const float* __restrict__ qs, const float* __restrict__ qt,
    const float* __restrict__ kb, const float* __restrict__ ks, const float* __restrict__ kt,
    const float* __restrict__ vb, const float* __restrict__ vs, const float* __restrict__ vt,
    bf16* __restrict__ qf, bf16* __restrict__ kf, bf16* __restrict__ v4) {
  __shared__ __align__(16) char lds[2][32768];  // [buf][A 16KB | B 16KB]
  const int NWG = 12 * 208;  // 2496, %8==0
  int id = blockIdx.x;
  int id2 = (id & 7) * (NWG >> 3) + (id >> 3);  // XCD-contiguous
  int mt = id2 % 12, nt = id2 / 12;
  int m0 = mt * 128, n0 = nt * 128;
  int tid = threadIdx.x, lane = tid & 63;
  int wv = tid >> 6, wm = wv >> 1, wn = wv & 1;

  f32x4 acc[4][4];
#pragma unroll
  for (int mi = 0; mi < 4; ++mi)
#pragma unroll
    for (int ni = 0; ni < 4; ++ni)
#pragma unroll
      for (int r = 0; r < 4; ++r) acc[mi][ni][r] = 0.f;

  auto stage = [&](int buf, int t) {
    int k0 = t * 64;
#pragma unroll
    for (int j = 0; j < 4; ++j) {
      int gi = tid + j * 256;
      int row = gi >> 3, g = gi & 7;
      int sk = k0 + ((g ^ (row & 7)) << 3);
      gll16(Wf + (size_t)(m0 + row) * DIM + sk, &lds[buf][gi * 16]);
      gll16(XT + (size_t)(n0 + row) * DIM + sk, &lds[buf][16384 + gi * 16]);
    }
  };
  auto compute = [&](int buf) {
    const char* Ab = lds[buf];
    const char* Bb = lds[buf] + 16384;
    int kq = lane >> 4, il = lane & 15;
#pragma unroll
    for (int ksb = 0; ksb < 2; ++ksb) {
      int G = ksb * 4 + kq;
      short8 af[4], bfr[4];
#pragma unroll
      for (int mi = 0; mi < 4; ++mi) {
        int row = wm * 64 + mi * 16 + il;
        af[mi] = *(const short8*)(Ab + row * 128 + ((G ^ (row & 7)) << 4));
      }
#pragma unroll
      for (int ni = 0; ni < 4; ++ni) {
        int row = wn * 64 + ni * 16 + il;
        bfr[ni] = *(const short8*)(Bb + row * 128 + ((G ^ (row & 7)) << 4));
      }
#pragma unroll
      for (int mi = 0; mi < 4; ++mi)
#pragma unroll
        for (int ni = 0; ni < 4; ++ni)
          acc[mi][ni] = __builtin_amdgcn_mfma_f32_16x16x32_bf16(af[mi], bfr[ni], acc[mi][ni], 0, 0, 0);
    }
  };

  stage(0, 0);
  __syncthreads();
  for (int t = 0; t < 6; ++t) {
    if (t < 5) stage((t + 1) & 1, t + 1);
    compute(t & 1);
    __syncthreads();
  }

  int cq = lane >> 4, cn = lane & 15;
#pragma unroll
  for (int mi = 0; mi < 4; ++mi) {
    int mbase = m0 + wm * 64 + mi * 16;
    const float *bp, *sp, *tp;
    int segbase, segid;
    if (mbase < 256)      { bp = qb; sp = qs; tp = qt; segbase = 0;   segid = 0; }
    else if (mbase < 512) { bp = kb; sp = ks; tp = kt; segbase = 256; segid = 1; }
    else                  { bp = vb; sp = vs; tp = vt; segbase = 512; segid = 2; }
#pragma unroll
    for (int r = 0; r < 4; ++r) {
      int ms = mbase - segbase + cq * 4 + r;
      float bi = bp[ms], sc = sp[ms], tt = tp[ms];
#pragma unroll
      for (int ni = 0; ni < 4; ++ni) {
        int n = n0 + wn * 64 + ni * 16 + cn;
        int b = n / NPAD;
        int nn = n - b * NPAD;
        float y = (acc[mi][ni][r] + bi) * sc + tt;
        y = (nn < NPIX) ? y : 0.f;
        if (segid == 2) {
          v4[((size_t)b * DH + ms) * VP + nn] = f2b(y);
        } else {
          bf16* dst = segid ? kf : qf;
          dst[(((size_t)b * NH + (ms >> 5)) * QROWS + nn) * KD + (ms & 31)] = f2b(y);
        }
      }
    }
  }
}

// ---------- zero v4 pad cols [208,224) ----------
__global__ __launch_bounds__(256) void k_vpad(bf16* __restrict__ v4) {
  int i = blockIdx.x * 256 + threadIdx.x;
  int tot = NB * DH * 16;
  if (i < tot) {
    int row = i >> 4, c = i & 15;
    v4[(size_t)row * VP + 208 + c] = f2b(0.f);
  }
}

// ---------- final projection: LDS-staged 128x128 tile GEMM, fp32 out ----------
__global__ __launch_bounds__(256, 2) void k_p2(
    const bf16* __restrict__ Pw, const bf16* __restrict__ OT,
    const float* __restrict__ pb, const float* __restrict__ ps, const float* __restrict__ pt,
    float* __restrict__ out) {
  __shared__ __align__(16) char lds[2][32768];
  const int NWG = 3 * 208;  // 624, %8==0
  int id = blockIdx.x;
  int id2 = (id & 7) * (NWG >> 3) + (id >> 3);
  int mt = id2 % 3, nt = id2 / 3;
  int m0 = mt * 128, n0 = nt * 128;
  int tid = threadIdx.x, lane = tid & 63;
  int wv = tid >> 6, wm = wv >> 1, wn = wv & 1;

  f32x4 acc[4][4];
#pragma unroll
  for (int mi = 0; mi < 4; ++mi)
#pragma unroll
    for (int ni = 0; ni < 4; ++ni)
#pragma unroll
      for (int r = 0; r < 4; ++r) acc[mi][ni][r] = 0.f;

  auto stage = [&](int buf, int t) {
    int k0 = t * 64;
#pragma unroll
    for (int j = 0; j < 4; ++j) {
      int gi = tid + j * 256;
      int row = gi >> 3, g = gi & 7;
      int sk = k0 + ((g ^ (row & 7)) << 3);
      gll16(Pw + (size_t)(m0 + row) * DH + sk, &lds[buf][gi * 16]);
      gll16(OT + (size_t)(n0 + row) * DH + sk, &lds[buf][16384 + gi * 16]);
    }
  };
  auto compute = [&](int buf) {
    const char* Ab = lds[buf];
    const char* Bb = lds[buf] + 16384;
    int kq = lane >> 4, il = lane & 15;
#pragma unroll
    for (int ksb = 0; ksb < 2; ++ksb) {
      int G = ksb * 4 + kq;
      short8 af[4], bfr[4];
#pragma unroll
      for (int mi = 0; mi < 4; ++mi) {
        int row = wm * 64 + mi * 16 + il;
        af[mi] = *(const short8*)(Ab + row * 128 + ((G ^ (row & 7)) << 4));
      }
#pragma unroll
      for (int ni = 0; ni < 4; ++ni) {
        int row = wn * 64 + ni * 16 + il;
        bfr[ni] = *(const short8*)(Bb + row * 128 + ((G ^ (row & 7)) << 4));
      }
#pragma unroll
      for (int mi = 0; mi < 4; ++mi)
#pragma unroll
        for (int ni = 0; ni < 4; ++ni)
          acc[mi][ni] = __builtin_amdgcn_mfma_f32_16x16x32_bf16(af[mi], bfr[ni], acc[mi][ni], 0, 0, 0);
    }
  };

  stage(0, 0);
  __syncthreads();
  for (int t = 0; t < 16; ++t) {
    if (t < 15) stage((t + 1) & 1, t + 1);
    compute(t & 1);
    __syncthreads();
  }

  int cq = lane >> 4, cn = lane & 15;
#pragma unroll
  for (int mi = 0; mi < 4; ++mi) {
#pragma unroll
    for (int r = 0; r < 4; ++r) {
      int m = m0 + wm * 64 + mi * 16 + cq * 4 + r;
      float bi = pb[m], sc = ps[m], tt = pt[m];
#pragma unroll
      for (int ni = 0; ni < 4; ++ni) {
        int n = n0 + wn * 64 + ni * 16 + cn;
        int b = n / NPAD;
        int nn = n - b * NPAD;
        if (nn < NPIX)
          out[((size_t)b * DIM + m) * NPIX + nn] = (acc[mi][ni][r] + bi) * sc + tt;
      }
    }
  }
}

// ---------- depthwise 3x3 + BN, fused with per-channel column sums ----------
__global__ __launch_bounds__(256) void k_dwv(
    const bf16* __restrict__ v4, const float* __restrict__ lvw,
    const float* __restrict__ lvb, const float* __restrict__ lvs,
    const float* __restrict__ lvt, bf16* __restrict__ vl,
    float* __restrict__ vcs) {
  int blk = blockIdx.x;
  int b = blk >> 8, cg = blk & 255;
  int lc = threadIdx.x >> 6, px = threadIdx.x & 63;
  int ch = cg * 4 + lc;
  const bf16* src = v4 + ((size_t)b * DH + ch) * VP;
  float w[9];
#pragma unroll
  for (int i = 0; i < 9; ++i) w[i] = lvw[ch * 9 + i];
  float bb = lvb[ch], ss = lvs[ch], tt = lvt[ch];
  bf16* dst = vl + ((size_t)b * DH + ch) * NPIX;
  float csum = 0.f;
  for (int p = px; p < NPIX; p += 64) {
    int ri = p / 14, ci = p - ri * 14;
    float s = 0.f;
#pragma unroll
    for (int dy = -1; dy <= 1; ++dy)
#pragma unroll
      for (int dx = -1; dx <= 1; ++dx) {
        int rr = ri + dy, cc = ci + dx;
        if (rr >= 0 && rr < 14 && cc >= 0 && cc < 14)
          s += w[(dy + 1) * 3 + dx + 1] * b2f(src[rr * 14 + cc]);
      }
    csum += b2f(src[p]);
    dst[p] = f2b((s + bb) * ss + tt);
  }
  csum += __shfl_xor(csum, 1);
  csum += __shfl_xor(csum, 2);
  csum += __shfl_xor(csum, 4);
  csum += __shfl_xor(csum, 8);
  csum += __shfl_xor(csum, 16);
  csum += __shfl_xor(csum, 32);
  if (px == 0) vcs[b * DH + ch] = csum;
}

// ---------- attention ----------
// S: bf16 [8 heads][16 rows][224 cols], row rotate-swizzled. 57344 B static LDS.
#define SROW 448  // bytes per S row
__device__ __forceinline__ int saddr(int g, int i, int j) {
  int r = j * 2 + ((i & 7) << 4);
  if (r >= SROW) r -= SROW;
  return (g * 16 + i) * SROW + r;
}

__global__ __launch_bounds__(512, 2) void k_att(
    const bf16* __restrict__ qf, const bf16* __restrict__ kf,
    const bf16* __restrict__ v4, const bf16* __restrict__ vl,
    const float* __restrict__ vcs,
    const float* __restrict__ th1w, const float* __restrict__ th1b,
    const float* __restrict__ th2w, const float* __restrict__ th2b,
    const float* __restrict__ ab, bf16* __restrict__ OT) {
  __shared__ __align__(16) char smem[NH * 16 * SROW];  // 57344 B
  __shared__ float ab2[NH * NPIX];                     // 6272 B
  __shared__ float c1s[64];
  __shared__ float c2s[64];
  __shared__ float smInv[NH * 16];                     // per-row 1/sum
  // batch->XCD affinity: all 13 Q-tiles of a batch share one XCD's L2.
  int id = blockIdx.x;            // 1664 linear
  int xcd = id & 7;
  int rest = id >> 3;             // [0,208)
  int qt = rest % 13;
  int b = (rest / 13) * 8 + xcd;  // [0,128), b%8 == xcd
  int i0 = qt * 16;
  int tid = threadIdx.x;
  int wave = tid >> 6, lane = tid & 63;
  int il = lane & 15, kh = lane >> 4;

  if (tid < 64) {
    c1s[tid] = th1w[tid] * SCALE;
    c2s[tid] = th2w[tid];
  }
  for (int pos = tid; pos < NH * NPIX; pos += 512) {
    int g = pos / NPIX, off = pos - g * NPIX;
    float s = th1b[g];
#pragma unroll
    for (int h = 0; h < 8; ++h)
      s += th1w[g * 8 + h] * ab[h * NPIX + off];
    ab2[pos] = s;
  }
  // ---- QK^T, head = wave; 16 q-rows x 208 k-rows, raw qk -> S (bf16) ----
  {
    const bf16* qp = qf + ((size_t)b * NH + wave) * QROWS * KD;
    const bf16* kp = kf + ((size_t)b * NH + wave) * QROWS * KD;
    short8 a = *(const short8*)(qp + (i0 + il) * KD + kh * 8);
    for (int jt = 0; jt < 13; ++jt) {
      short8 bb = *(const short8*)(kp + (jt * 16 + il) * KD + kh * 8);
      f32x4 acc = {0.f, 0.f, 0.f, 0.f};
      acc = __builtin_amdgcn_mfma_f32_16x16x32_bf16(a, bb, acc, 0, 0, 0);
      int j = jt * 16 + il;
#pragma unroll
      for (int r = 0; r < 4; ++r)
        *(bf16*)(smem + saddr(wave, kh * 4 + r, j)) = f2b(acc[r]);
    }
  }
  __syncthreads();
  // ---- pass A: talking-head-1 mix (with SCALE) + relative-position bias ----
  for (int pos = tid; pos < 16 * NPIX; pos += 512) {
    int i = pos / NPIX, j = pos - i * NPIX;
    float sv[8];
#pragma unroll
    for (int h = 0; h < 8; ++h) sv[h] = b2f(*(const bf16*)(smem + saddr(h, i, j)));
    int ia = i0 + i; if (ia > 195) ia = 195;
    int ri = ia / 14, ci = ia - ri * 14;
    int rj = j / 14, cj = j - rj * 14;
    int dr = ri > rj ? ri - rj : rj - ri;
    int dc = ci > cj ? ci - cj : cj - ci;
    int off = dr * 14 + dc;
    float outv[8];
#pragma unroll
    for (int g = 0; g < 8; ++g) {
      float s = ab2[g * NPIX + off];
#pragma unroll
      for (int h = 0; h < 8; ++h) s += c1s[g * 8 + h] * sv[h];
      outv[g] = s;
    }
#pragma unroll
    for (int g = 0; g < 8; ++g)
      *(bf16*)(smem + saddr(g, i, j)) = f2b(outv[g]);
  }
  __syncthreads();
  // ---- softmax: vectorized max + exp passes; store UNNORMALIZED exp; 1/sum -> smInv ----
  {
    int row = tid >> 2, part = tid & 3;  // 128 rows = 8 heads x 16
    int g = row >> 4, i = row & 15;
    int jb = part * 52;
    int n4 = (part == 3) ? 10 : 13;  // part 3 covers j in [156,196)
    float m = -1e30f;
    for (int it = 0; it < n4; ++it) {
      short4v v = *(const short4v*)(smem + saddr(g, i, jb + it * 4));
#pragma unroll
      for (int t = 0; t < 4; ++t) m = fmaxf(m, us2f((unsigned short)v[t]));
    }
    m = fmaxf(m, __shfl_xor(m, 1));
    m = fmaxf(m, __shfl_xor(m, 2));
    float s = 0.f;
    for (int it = 0; it < n4; ++it) {
      char* p = smem + saddr(g, i, jb + it * 4);
      short4v v = *(const short4v*)p;
      short4v w;
#pragma unroll
      for (int t = 0; t < 4; ++t) {
        float e = __expf(us2f((unsigned short)v[t]) - m);
        s += e;
        w[t] = f2us(e);
      }
      *(short4v*)p = w;
    }
    if (part == 3) {  // zero pad cols [196,224)
      short4v z = {0, 0, 0, 0};
#pragma unroll
      for (int it = 0; it < 7; ++it)
        *(short4v*)(smem + saddr(g, i, 196 + it * 4)) = z;
    }
    s += __shfl_xor(s, 1);
    s += __shfl_xor(s, 2);
    if (part == 0) smInv[row] = 1.f / s;
  }
  __syncthreads();
  // ---- pass C: talking-head-2 mix with folded 1/sum (scalar, R5 structure) ----
  for (int pos = tid; pos < 16 * NPIX; pos += 512) {
    int i = pos / NPIX, j = pos - i * NPIX;
    float pv[8];
#pragma unroll
    for (int g = 0; g < 8; ++g)
      pv[g] = b2f(*(const bf16*)(smem + saddr(g, i, j))) * smInv[g * 16 + i];
#pragma unroll
    for (int g2 = 0; g2 < 8; ++g2) {
      float s = 0.f;
#pragma unroll
      for (int g = 0; g < 8; ++g) s += c2s[g2 * 8 + g] * pv[g];
      *(bf16*)(smem + saddr(g2, i, j)) = f2b(s);
    }
  }
  __syncthreads();
  // ---- PV: O_g = P_g @ V_g^T, +th2b*colsum(v) +vl, relu, store transposed ----
  {
    int g = wave;
    f32x4 oacc[8];
#pragma unroll
    for (int dt = 0; dt < 8; ++dt)
#pragma unroll
      for (int r = 0; r < 4; ++r) oacc[dt][r] = 0.f;
    const bf16* vbase = v4 + ((size_t)b * DH + g * DHEAD) * VP;
    for (int ks = 0; ks < 7; ++ks) {
      short8 pa = *(const short8*)(smem + saddr(g, il, ks * 32 + kh * 8));
#pragma unroll
      for (int dt = 0; dt < 8; ++dt) {
        short8 bv = *(const short8*)(vbase + (size_t)(dt * 16 + il) * VP + ks * 32 + kh * 8);
        oacc[dt] = __builtin_amdgcn_mfma_f32_16x16x32_bf16(pa, bv, oacc[dt], 0, 0, 0);
      }
    }
    float t2b = th2b[g];
#pragma unroll
    for (int dt = 0; dt < 8; ++dt) {
      int ch = g * DHEAD + dt * 16 + il;
      float csv = vcs[b * DH + ch] * t2b;
#pragma unroll
      for (int r = 0; r < 4; ++r) {
        int n = i0 + kh * 4 + r;
        if (n < NPIX) {
          float val = oacc[dt][r] + csv + b2f(vl[((size_t)b * DH + ch) * NPIX + n]);
          OT[((size_t)b * NPAD + n) * DH + ch] = f2b(fmaxf(val, 0.f));
        } else {
          OT[((size_t)b * NPAD + n) * DH + ch] = f2b(0.f);
        }
      }
    }
  }
}

extern "C" void kernel_launch(void* const* d_in, const int* in_sizes, int n_in,
                              void* d_out, int out_size, void* d_ws, size_t ws_size,
                              hipStream_t stream) {
  const float* x    = (const float*)d_in[0];
  const float* qw   = (const float*)d_in[1];
  const float* qb   = (const float*)d_in[2];
  const float* q_s  = (const float*)d_in[3];
  const float* q_t  = (const float*)d_in[4];
  const float* kw   = (const float*)d_in[5];
  const float* kb   = (const float*)d_in[6];
  const float* k_s  = (const float*)d_in[7];
  const float* k_t  = (const float*)d_in[8];
  const float* vw   = (const float*)d_in[9];
  const float* vb   = (const float*)d_in[10];
  const float* v_s  = (const float*)d_in[11];
  const float* v_t  = (const float*)d_in[12];
  const float* lvw  = (const float*)d_in[13];
  const float* lvb  = (const float*)d_in[14];
  const float* lv_s = (const float*)d_in[15];
  const float* lv_t = (const float*)d_in[16];
  const float* th1w = (const float*)d_in[17];
  const float* th1b = (const float*)d_in[18];
  const float* th2w = (const float*)d_in[19];
  const float* th2b = (const float*)d_in[20];
  const float* ab   = (const float*)d_in[21];
  const float* pw   = (const float*)d_in[22];
  const float* pb   = (const float*)d_in[23];
  const float* p_s  = (const float*)d_in[24];
  const float* p_t  = (const float*)d_in[25];

  char* ws = (char*)d_ws;
  size_t off = 0;
  auto alloc = [&](size_t bytes) {
    char* p = ws + off;
    off += (bytes + 255) & ~(size_t)255;
    return p;
  };
  // region0: XT (B,208,384 bf16) aliased with OT (B,208,1024 bf16)
  char* region0 = alloc((size_t)NB * NPAD * DH * 2);
  bf16* XT  = (bf16*)region0;
  bf16* OT  = (bf16*)region0;
  bf16* qfb = (bf16*)alloc((size_t)NB * NH * QROWS * KD * 2);
  bf16* kfb = (bf16*)alloc((size_t)NB * NH * QROWS * KD * 2);
  bf16* v4  = (bf16*)alloc((size_t)NB * DH * VP * 2);
  bf16* vlb = (bf16*)alloc((size_t)NB * DH * NPIX * 2);
  float* vcs = (float*)alloc((size_t)NB * DH * 4);
  bf16* wf  = (bf16*)alloc((size_t)1536 * DIM * 2);  // fused Q|K|V weights
  bf16* wpb = (bf16*)alloc((size_t)DIM * DH * 2);    // immediately follows wf
  (void)ws_size; (void)in_sizes; (void)n_in; (void)out_size;

  k_cvt4<<<dim3(3840), 256, 0, stream>>>(qw, kw, vw, pw, wf);
  k_xt<<<dim3(12, 7, NB), 256, 0, stream>>>(x, XT);
  k_qkv2<<<dim3(2496), 256, 0, stream>>>(wf, XT, qb, q_s, q_t, kb, k_s, k_t,
                                         vb, v_s, v_t, qfb, kfb, v4);
  k_vpad<<<dim3((NB * DH * 16 + 255) / 256), 256, 0, stream>>>(v4);
  k_dwv<<<dim3(NB * 256), 256, 0, stream>>>(v4, lvw, lvb, lv_s, lv_t, vlb, vcs);
  k_att<<<dim3(1664), 512, 0, stream>>>(qfb, kfb, v4, vlb, vcs,
                                        th1w, th1b, th2w, th2b, ab, OT);
  k_p2<<<dim3(624), 256, 0, stream>>>(wpb, OT, pb, p_s, p_t, (float*)d_out);
}